// Round 9
// baseline (191.948 us; speedup 1.0000x reference)
//
#include <hip/hip_runtime.h>
#include <math.h>

#define NN 500
#define TT 48
#define NT 24000   // NN*TT
#define NF4 6000   // NT/4

typedef float f4v __attribute__((ext_vector_type(4)));

// ---------- kernel 0a: row sums of s ----------
__global__ void k_srow(const float* __restrict__ s, float* __restrict__ srow) {
    int r = blockIdx.x;
    int l = threadIdx.x;
    float v = 0.f;
    for (int j = l; j < NN; j += 64) v += s[r * NN + j];
    #pragma unroll
    for (int o = 32; o; o >>= 1) v += __shfl_xor(v, o);
    if (l == 0) srow[r] = v;
}

// ---------- kernel 1: per-(b,c) softmax over 24000 folded to per-n sums ----------
// TWO-PHASE load/compute split: phase A issues all 12 dwordx4 loads into
// registers with no consumers in between (12 KB in flight per wave, vs ~1 KB
// when each load is consumed by exp math before the next issues); phase B
// does the math as loads land (compiler inserts descending vmcnt waits).
// rs reconstructed from srow staged in LDS (round-8 win, kept).
__launch_bounds__(512, 4)
__global__ void k_p1(const float* __restrict__ x, const float* __restrict__ srow,
                     float* __restrict__ xws) {
    __shared__ float p[6144];          // per-float4 contributions (f-indexed)
    __shared__ __align__(16) float sr[512];   // srow staged (500 used)
    __shared__ float redm[8], reds[8];
    int bc = blockIdx.x;
    int tid = threadIdx.x;
    int w = tid >> 6, l = tid & 63;
    int f0 = w * 768 + l;

    if (tid < NN) sr[tid] = srow[tid];
    __syncthreads();

    const f4v* xp = (const f4v*)x + (size_t)bc * NF4;

    // ---- PHASE A: batch-issue all 12 loads (only i>=9 can exceed NF4) ----
    f4v xv[12];
    #pragma unroll
    for (int i = 0; i < 9; i++) xv[i] = xp[f0 + i * 64];
    #pragma unroll
    for (int i = 9; i < 12; i++) {
        int f = f0 + i * 64;
        xv[i] = xp[(f < NF4) ? f : (NF4 - 1)];
    }

    // ---- PHASE B: math (consumes loads in issue order) ----
    float sf[12], ml[12];
    float m = 0.f;                     // relu output >= 0, so 0 is a safe identity
    #pragma unroll
    for (int i = 0; i < 12; i++) {
        int f = f0 + i * 64;
        int fc = (f < NF4) ? f : (NF4 - 1);
        float msk = (f < NF4) ? 1.f : 0.f;   // 1 for all i<9
        int kk = 4 * fc;
        int ti = kk / 500;             // magic-mul div
        int v  = kk - ti * 500;        // multiple of 4
        float tt = (float)(TT - 1 - ti) * 0.8f;
        float4 sv = *(const float4*)(sr + v);
        float y0 = fmaxf(xv[i].x * (tt + sv.x) * 0.125f, 0.f);
        float y1 = fmaxf(xv[i].y * (tt + sv.y) * 0.125f, 0.f);
        float y2 = fmaxf(xv[i].z * (tt + sv.z) * 0.125f, 0.f);
        float y3 = fmaxf(xv[i].w * (tt + sv.w) * 0.125f, 0.f);
        float mm = fmaxf(fmaxf(y0, y1), fmaxf(y2, y3));
        float sfi = __expf(y0 - mm) + __expf(y1 - mm)
                  + __expf(y2 - mm) + __expf(y3 - mm);
        sf[i] = sfi * msk;
        ml[i] = mm;                    // clamped dup echoes a real element: safe in max
        m = fmaxf(m, mm);
    }

    // block max over 8 waves
    #pragma unroll
    for (int o = 32; o; o >>= 1) m = fmaxf(m, __shfl_xor(m, o));
    if (l == 0) redm[w] = m;
    __syncthreads();
    float M = redm[0];
    #pragma unroll
    for (int i = 1; i < 8; i++) M = fmaxf(M, redm[i]);

    // rescale per-float4 sums -> LDS (conflict-free writes), lane total -> Z
    float tot = 0.f;
    #pragma unroll
    for (int i = 0; i < 12; i++) {
        float cf = sf[i] * __expf(ml[i] - M);
        p[f0 + i * 64] = cf;
        tot += cf;
    }
    #pragma unroll
    for (int o = 32; o; o >>= 1) tot += __shfl_xor(tot, o);
    if (l == 0) reds[w] = tot;
    __syncthreads();
    float Z = 0.f;
    #pragma unroll
    for (int i = 0; i < 8; i++) Z += reds[i];

    // thread n gathers node n's 12 consecutive partials
    if (tid < NN) {
        const float* pp = p + tid * 12;
        float sn = 0.f;
        #pragma unroll
        for (int j = 0; j < 12; j++) sn += pp[j];
        xws[(size_t)bc * NN + tid] = sn / Z;
    }
}

// ---------- kernel 2: gram (X^T X over C=64) fused with row softmax ----------
// (unchanged for clean attribution)
__launch_bounds__(512, 4)
__global__ void k_p2(const float* __restrict__ xws, float* __restrict__ out) {
    __shared__ __align__(16) float Xs[32 * NN + 16];
    int b = blockIdx.y;
    int rt8 = blockIdx.x;   // 0..7
    int tid = threadIdx.x;

    int rt = tid >> 6, cx = tid & 63;
    int r0 = rt8 * 64 + rt * 8;
    int cb0 = cx * 4, cb1 = cx * 4 + 256;

    float acc[8][8];
    #pragma unroll
    for (int i = 0; i < 8; i++)
        #pragma unroll
        for (int j = 0; j < 8; j++) acc[i][j] = 0.f;

    for (int cbk = 0; cbk < 2; cbk++) {
        const float4* src4 = (const float4*)(xws + ((size_t)b * 64 + 32 * cbk) * NN);
        __syncthreads();                 // protect previous Xs use
        #pragma unroll
        for (int i = 0; i < 8; i++) {
            int idx = tid + i * 512;
            if (idx < 4000) ((float4*)Xs)[idx] = src4[idx];
        }
        if (tid < 16) Xs[32 * NN + tid] = 0.f;   // zero the guard pad
        __syncthreads();

        #pragma unroll 4
        for (int c = 0; c < 32; c++) {
            const float* row = Xs + c * NN;
            float4 a0 = *(const float4*)(row + r0);       // broadcast (uniform addr)
            float4 a1 = *(const float4*)(row + r0 + 4);
            float4 b0 = *(const float4*)(row + cb0);      // lanes contiguous 16B
            float4 b1 = *(const float4*)(row + cb1);
            float av[8] = {a0.x, a0.y, a0.z, a0.w, a1.x, a1.y, a1.z, a1.w};
            float bv[8] = {b0.x, b0.y, b0.z, b0.w, b1.x, b1.y, b1.z, b1.w};
            #pragma unroll
            for (int i = 0; i < 8; i++)
                #pragma unroll
                for (int j = 0; j < 8; j++)
                    acc[i][j] = fmaf(av[i], bv[j], acc[i][j]);
        }
    }

    bool c1v = (cx <= 60);
    size_t ob = (size_t)b * (NN * NN);
    #pragma unroll 1
    for (int ri = 0; ri < 8; ri++) {
        int r = r0 + ri;
        if (r >= NN) break;         // wave-uniform
        float u[8];
        #pragma unroll
        for (int j = 0; j < 8; j++) u[j] = fmaxf(acc[ri][j], 0.f) * 0.125f;
        float mx = fmaxf(fmaxf(u[0], u[1]), fmaxf(u[2], u[3]));
        if (c1v) mx = fmaxf(mx, fmaxf(fmaxf(u[4], u[5]), fmaxf(u[6], u[7])));
        #pragma unroll
        for (int o = 32; o; o >>= 1) mx = fmaxf(mx, __shfl_xor(mx, o));

        float e[8];
        float es = 0.f;
        #pragma unroll
        for (int j = 0; j < 4; j++) { e[j] = __expf(u[j] - mx); es += e[j]; }
        if (c1v) {
            #pragma unroll
            for (int j = 4; j < 8; j++) { e[j] = __expf(u[j] - mx); es += e[j]; }
        }
        #pragma unroll
        for (int o = 32; o; o >>= 1) es += __shfl_xor(es, o);
        float inv = 1.f / es;

        float4 w0 = make_float4(e[0] * inv, e[1] * inv, e[2] * inv, e[3] * inv);
        *(float4*)(out + ob + (size_t)r * NN + cb0) = w0;
        if (c1v) {
            float4 w1 = make_float4(e[4] * inv, e[5] * inv, e[6] * inv, e[7] * inv);
            *(float4*)(out + ob + (size_t)r * NN + cb1) = w1;
        }
    }
}

// ---------- CEILING PROBE (temporary, this round only) ----------
// Pure coalesced read of the FIRST HALF of x (196.6 MB), wave-reduced, 32 KB
// written to far scratch. Its marginal cost = true achievable rate for this
// exact stream shape: ~31 us @6.3 TB/s vs ~60 us @3.3 TB/s.
__launch_bounds__(256, 8)
__global__ void k_bw(const float* __restrict__ x, float* __restrict__ sink) {
    int blk = blockIdx.x;              // 2048 blocks = bc rows 0..2047
    int tid = threadIdx.x;             // 256 threads
    const f4v* xp = (const f4v*)x + (size_t)blk * NF4;
    float acc = 0.f;
    #pragma unroll
    for (int i = 0; i < 23; i++) {     // 23*256 = 5888 < 6000
        f4v v = xp[tid + i * 256];
        acc += v.x + v.y + v.z + v.w;
    }
    { // tail 5888..5999
        int f = 5888 + tid;
        if (f < NF4) { f4v v = xp[f]; acc += v.x + v.y + v.z + v.w; }
    }
    #pragma unroll
    for (int o = 32; o; o >>= 1) acc += __shfl_xor(acc, o);
    if ((tid & 63) == 0) sink[blk * 4 + (tid >> 6)] = acc;
}

extern "C" void kernel_launch(void* const* d_in, const int* in_sizes, int n_in,
                              void* d_out, int out_size, void* d_ws, size_t ws_size,
                              hipStream_t stream) {
    const float* x = (const float*)d_in[0];   // [64,64,500,48]
    const float* s = (const float*)d_in[1];   // [500,500]
    float* out = (float*)d_out;               // [64,500,500]
    float* wsf = (float*)d_ws;

    float* srow = wsf;             // 500 floats
    float* xws  = wsf + 32768;     // 64*64*500 = 2,048,000 floats (~8.2 MB)
    float* sink = wsf + 4 * 1024 * 1024;   // probe scratch (32 KB), far from live data

    k_srow<<<NN, 64, 0, stream>>>(s, srow);
    k_p1<<<64 * 64, 512, 0, stream>>>(x, srow, xws);
    dim3 g2(8, 64);
    k_p2<<<g2, 512, 0, stream>>>(xws, out);
    k_bw<<<2048, 256, 0, stream>>>(x, sink);   // ceiling probe — remove next round
}

// Round 10
// 166.551 us; speedup vs baseline: 1.1525x; 1.1525x over previous
//
#include <hip/hip_runtime.h>
#include <math.h>

#define NN 500
#define TT 48
#define NT 24000   // NN*TT
#define NF4 6000   // NT/4

typedef float f4v __attribute__((ext_vector_type(4)));

// ---------- kernel 0a: row sums of s ----------
__global__ void k_srow(const float* __restrict__ s, float* __restrict__ srow) {
    int r = blockIdx.x;
    int l = threadIdx.x;
    float v = 0.f;
    for (int j = l; j < NN; j += 64) v += s[r * NN + j];
    #pragma unroll
    for (int o = 32; o; o >>= 1) v += __shfl_xor(v, o);
    if (l == 0) srow[r] = v;
}

// ---------- kernel 1: BARRIER-FREE per-wave softmax partials ----------
// Each wave owns 64 nodes = 768 consecutive float4s; the per-node gather is
// wave-local (LDS region private per wave, lgkmcnt-guarded, no __syncthreads).
// Cross-wave softmax coupling (block max/sum) is deferred: wave writes
// un-normalized sn = sum_t exp(y - Mw) and (Mw, Zw); k_mz folds them into
// per-(bc,wave) factors; p2 applies the factor while staging.
// 256-thread blocks, 2 per bc row (8192 blocks) -> free-running waves keep
// the memory pipe busy (the k_bw probe shape, which hit ~full stream BW).
__launch_bounds__(256, 4)
__global__ void k_p1(const float* __restrict__ x, const float* __restrict__ srow,
                     float* __restrict__ xraw, float* __restrict__ mz) {
    __shared__ float p[3072];                 // 4 waves x 768 private floats
    __shared__ __align__(16) float sr[512];   // srow staged (500 used)
    int bid = blockIdx.x;
    int bc = bid >> 1, half = bid & 1;
    int tid = threadIdx.x;
    int w = tid >> 6, l = tid & 63;
    int fl0 = w * 768 + l;                    // local float4 index in block range
    int f0 = half * 3072 + fl0;               // global float4 index in row

    sr[tid] = srow[(tid < NN) ? tid : (NN - 1)];
    int t2 = tid + 256;
    sr[t2] = (t2 < NN) ? srow[t2] : 0.f;
    __syncthreads();                          // only barrier; overlaps load issue

    const f4v* xp = (const f4v*)x + (size_t)bc * NF4;

    // ---- phase A: batch-issue 12 loads (clamp only reachable for i>=9) ----
    f4v xv[12];
    #pragma unroll
    for (int i = 0; i < 9; i++) xv[i] = xp[f0 + i * 64];
    #pragma unroll
    for (int i = 9; i < 12; i++) {
        int f = f0 + i * 64;
        xv[i] = xp[(f < NF4) ? f : (NF4 - 1)];
    }

    // ---- phase B: per-float4 (sf, ml), wave max ----
    float sf[12], ml[12];
    float m = 0.f;                            // relu >= 0 -> 0 is safe identity
    #pragma unroll
    for (int i = 0; i < 12; i++) {
        int f = f0 + i * 64;
        int fc = (f < NF4) ? f : (NF4 - 1);
        float msk = (f < NF4) ? 1.f : 0.f;
        int kk = 4 * fc;
        int ti = kk / 500;                    // magic-mul div
        int v  = kk - ti * 500;               // multiple of 4
        float tt = (float)(TT - 1 - ti) * 0.8f;
        float4 sv = *(const float4*)(sr + v);
        float y0 = fmaxf(xv[i].x * (tt + sv.x) * 0.125f, 0.f);
        float y1 = fmaxf(xv[i].y * (tt + sv.y) * 0.125f, 0.f);
        float y2 = fmaxf(xv[i].z * (tt + sv.z) * 0.125f, 0.f);
        float y3 = fmaxf(xv[i].w * (tt + sv.w) * 0.125f, 0.f);
        float mm = fmaxf(fmaxf(y0, y1), fmaxf(y2, y3));
        float sfi = __expf(y0 - mm) + __expf(y1 - mm)
                  + __expf(y2 - mm) + __expf(y3 - mm);
        sf[i] = sfi * msk;
        ml[i] = mm;                           // clamped dup echoes a real element
        m = fmaxf(m, mm);
    }
    #pragma unroll
    for (int o = 32; o; o >>= 1) m = fmaxf(m, __shfl_xor(m, o));  // Mw (wave max)

    // ---- rescale to wave max, write wave-private LDS, wave sum Zw ----
    float tot = 0.f;
    #pragma unroll
    for (int i = 0; i < 12; i++) {
        float cf = sf[i] * __expf(ml[i] - m);
        p[fl0 + i * 64] = cf;
        tot += cf;
    }
    #pragma unroll
    for (int o = 32; o; o >>= 1) tot += __shfl_xor(tot, o);       // Zw

    // drain this wave's ds_writes before wave-local gather (no block barrier)
    asm volatile("s_waitcnt lgkmcnt(0)" ::: "memory");

    // ---- wave-local gather: node n = half*256 + 64w + l owns p[w*768+12l..+11] ----
    int n = half * 256 + w * 64 + l;
    if (n < NN) {
        const float4* pp = (const float4*)(p + w * 768 + l * 12);  // 48B-aligned
        float4 a = pp[0], b4 = pp[1], c4 = pp[2];
        float sn = a.x + a.y + a.z + a.w + b4.x + b4.y + b4.z + b4.w
                 + c4.x + c4.y + c4.z + c4.w;
        xraw[(size_t)bc * NN + n] = sn;
    }
    if (l == 0) {
        int wv = half * 4 + w;                // wave index within row, 0..7
        mz[((size_t)bc * 8 + wv) * 2 + 0] = m;
        mz[((size_t)bc * 8 + wv) * 2 + 1] = tot;
    }
}

// ---------- kernel 1b: fold per-wave (Mw, Zw) into factors ----------
// factor[bc][wv] = exp(Mw - M) / Z,  Z = sum_wv Zw * exp(Mw - M)
__global__ void k_mz(const float* __restrict__ mz, float* __restrict__ factor) {
    int bc = blockIdx.x * 256 + threadIdx.x;     // 16 blocks x 256 = 4096
    float Mw[8], Zw[8];
    float M = 0.f;
    #pragma unroll
    for (int wv = 0; wv < 8; wv++) {
        Mw[wv] = mz[((size_t)bc * 8 + wv) * 2 + 0];
        Zw[wv] = mz[((size_t)bc * 8 + wv) * 2 + 1];
        M = fmaxf(M, Mw[wv]);
    }
    float Z = 0.f;
    float e[8];
    #pragma unroll
    for (int wv = 0; wv < 8; wv++) {
        e[wv] = __expf(Mw[wv] - M);
        Z += Zw[wv] * e[wv];
    }
    float invZ = 1.f / Z;
    #pragma unroll
    for (int wv = 0; wv < 8; wv++)
        factor[(size_t)bc * 8 + wv] = e[wv] * invZ;
}

// ---------- kernel 2: gram (X^T X over C=64) fused with row softmax ----------
// Staging now applies the per-(bc,wave) softmax factor (normalization moved
// out of p1). factor table = 32 KB, L2-hot; one scalar mul per float4.
__launch_bounds__(512, 4)
__global__ void k_p2(const float* __restrict__ xraw, const float* __restrict__ factor,
                     float* __restrict__ out) {
    __shared__ __align__(16) float Xs[32 * NN + 16];
    int b = blockIdx.y;
    int rt8 = blockIdx.x;   // 0..7
    int tid = threadIdx.x;

    int rt = tid >> 6, cx = tid & 63;
    int r0 = rt8 * 64 + rt * 8;
    int cb0 = cx * 4, cb1 = cx * 4 + 256;

    float acc[8][8];
    #pragma unroll
    for (int i = 0; i < 8; i++)
        #pragma unroll
        for (int j = 0; j < 8; j++) acc[i][j] = 0.f;

    for (int cbk = 0; cbk < 2; cbk++) {
        const float4* src4 = (const float4*)(xraw + ((size_t)b * 64 + 32 * cbk) * NN);
        const float* fac = factor + ((size_t)b * 64 + 32 * cbk) * 8;
        __syncthreads();                 // protect previous Xs use
        #pragma unroll
        for (int i = 0; i < 8; i++) {
            int idx = tid + i * 512;
            if (idx < 4000) {
                int c = idx / 125;       // magic-mul div (125 float4 per channel)
                int n4 = idx - c * 125;
                float fct = fac[c * 8 + (n4 >> 4)];
                float4 v = src4[idx];
                v.x *= fct; v.y *= fct; v.z *= fct; v.w *= fct;
                ((float4*)Xs)[idx] = v;
            }
        }
        if (tid < 16) Xs[32 * NN + tid] = 0.f;   // zero the guard pad
        __syncthreads();

        #pragma unroll 4
        for (int c = 0; c < 32; c++) {
            const float* row = Xs + c * NN;
            float4 a0 = *(const float4*)(row + r0);       // broadcast (uniform addr)
            float4 a1 = *(const float4*)(row + r0 + 4);
            float4 b0 = *(const float4*)(row + cb0);      // lanes contiguous 16B
            float4 b1 = *(const float4*)(row + cb1);
            float av[8] = {a0.x, a0.y, a0.z, a0.w, a1.x, a1.y, a1.z, a1.w};
            float bv[8] = {b0.x, b0.y, b0.z, b0.w, b1.x, b1.y, b1.z, b1.w};
            #pragma unroll
            for (int i = 0; i < 8; i++)
                #pragma unroll
                for (int j = 0; j < 8; j++)
                    acc[i][j] = fmaf(av[i], bv[j], acc[i][j]);
        }
    }

    bool c1v = (cx <= 60);
    size_t ob = (size_t)b * (NN * NN);
    #pragma unroll 1
    for (int ri = 0; ri < 8; ri++) {
        int r = r0 + ri;
        if (r >= NN) break;         // wave-uniform
        float u[8];
        #pragma unroll
        for (int j = 0; j < 8; j++) u[j] = fmaxf(acc[ri][j], 0.f) * 0.125f;
        float mx = fmaxf(fmaxf(u[0], u[1]), fmaxf(u[2], u[3]));
        if (c1v) mx = fmaxf(mx, fmaxf(fmaxf(u[4], u[5]), fmaxf(u[6], u[7])));
        #pragma unroll
        for (int o = 32; o; o >>= 1) mx = fmaxf(mx, __shfl_xor(mx, o));

        float e[8];
        float es = 0.f;
        #pragma unroll
        for (int j = 0; j < 4; j++) { e[j] = __expf(u[j] - mx); es += e[j]; }
        if (c1v) {
            #pragma unroll
            for (int j = 4; j < 8; j++) { e[j] = __expf(u[j] - mx); es += e[j]; }
        }
        #pragma unroll
        for (int o = 32; o; o >>= 1) es += __shfl_xor(es, o);
        float inv = 1.f / es;

        float4 w0 = make_float4(e[0] * inv, e[1] * inv, e[2] * inv, e[3] * inv);
        *(float4*)(out + ob + (size_t)r * NN + cb0) = w0;
        if (c1v) {
            float4 w1 = make_float4(e[4] * inv, e[5] * inv, e[6] * inv, e[7] * inv);
            *(float4*)(out + ob + (size_t)r * NN + cb1) = w1;
        }
    }
}

extern "C" void kernel_launch(void* const* d_in, const int* in_sizes, int n_in,
                              void* d_out, int out_size, void* d_ws, size_t ws_size,
                              hipStream_t stream) {
    const float* x = (const float*)d_in[0];   // [64,64,500,48]
    const float* s = (const float*)d_in[1];   // [500,500]
    float* out = (float*)d_out;               // [64,500,500]
    float* wsf = (float*)d_ws;

    float* srow   = wsf;                        // 500 floats
    float* xraw   = wsf + 32768;                // 64*64*500 = 2,048,000 floats
    float* mz     = wsf + 32768 + 2048000;      // 4096*8*2 = 65,536 floats
    float* factor = wsf + 32768 + 2048000 + 65536;  // 4096*8 = 32,768 floats

    k_srow<<<NN, 64, 0, stream>>>(s, srow);
    k_p1<<<64 * 64 * 2, 256, 0, stream>>>(x, srow, xraw, mz);
    k_mz<<<16, 256, 0, stream>>>(mz, factor);
    dim3 g2(8, 64);
    k_p2<<<g2, 512, 0, stream>>>(xraw, factor, out);
}